// Round 19
// baseline (130.382 us; speedup 1.0000x reference)
//
#include <hip/hip_runtime.h>

typedef __bf16 bf16x8 __attribute__((ext_vector_type(8)));
typedef __bf16 bf16x4 __attribute__((ext_vector_type(4)));
typedef float f32x4 __attribute__((ext_vector_type(4)));

#define MFMA16(a,b,c) __builtin_amdgcn_mfma_f32_16x16x32_bf16((a),(b),(c),0,0,0)

__device__ __forceinline__ float fexp2(float x) { return __builtin_amdgcn_exp2f(x); }

__device__ __forceinline__ void gload_lds16(const void* g, void* l) {
    __builtin_amdgcn_global_load_lds(
        (const __attribute__((address_space(1))) void*)g,
        (__attribute__((address_space(3))) void*)l, 16, 0, 0);
}

// Problem constants: B=8 S=1024 IN=512 ORIG=64 E=512 H=8 hd=64
// q pre-scaled by 0.125*log2(e): softmax in base-2

__global__ __launch_bounds__(256) void k_convert(
    const float* __restrict__ x, const float* __restrict__ inp,
    const float* __restrict__ Wqkv, const float* __restrict__ Wo,
    __bf16* __restrict__ xc, __bf16* __restrict__ wq, __bf16* __restrict__ wo)
{
    const unsigned C1 = 589824u;
    const unsigned C2 = 110592u;
    unsigned i = blockIdx.x * 256u + threadIdx.x;
    if (i < C1) {
        unsigned e = i * 8u;
        unsigned m = e / 576u, k = e - m * 576u;
        const float* p = (k < 512u) ? x + (size_t)m * 512u + k
                                    : inp + (size_t)m * 64u + (k - 512u);
        f32x4 a = *(const f32x4*)p, b = *(const f32x4*)(p + 4);
        bf16x8 o;
#pragma unroll
        for (int j = 0; j < 4; ++j) { o[j] = (__bf16)a[j]; o[j + 4] = (__bf16)b[j]; }
        *(bf16x8*)&xc[e] = o;
    } else if (i < C1 + C2) {
        unsigned e = (i - C1) * 8u;
        f32x4 a = *(const f32x4*)&Wqkv[e], b = *(const f32x4*)&Wqkv[e + 4];
        bf16x8 o;
#pragma unroll
        for (int j = 0; j < 4; ++j) { o[j] = (__bf16)a[j]; o[j + 4] = (__bf16)b[j]; }
        *(bf16x8*)&wq[e] = o;
    } else {
        unsigned e = (i - C1 - C2) * 8u;
        f32x4 a = *(const f32x4*)&Wo[e], b = *(const f32x4*)&Wo[e + 4];
        bf16x8 o;
#pragma unroll
        for (int j = 0; j < 4; ++j) { o[j] = (__bf16)a[j]; o[j + 4] = (__bf16)b[j]; }
        *(bf16x8*)&wo[e] = o;
    }
}

// ---------------- QKV GEMM v3: BK=64 K-loop (9 iters), both-sides-swizzled staging ----------------
__global__ __launch_bounds__(256) void k_qkv_gemm(
    const __bf16* __restrict__ A, const __bf16* __restrict__ W,
    const float* __restrict__ bias,
    __bf16* __restrict__ q_ws, __bf16* __restrict__ k_ws, __bf16* __restrict__ vt_ws)
{
    const int K = 576;
    __shared__ __align__(16) char smem[32768];   // As 16K [128][64] | Bs 16K
    int m0 = blockIdx.x * 128, n0 = blockIdx.y * 128;
    int t = threadIdx.x, w = t >> 6, l = t & 63;
    int lo = l & 15, hi = l >> 4;
    int wr = w >> 1, wc = w & 1;

    // staging: LDS byte L = c*4096 + w*1024 + l*16 -> row r = c*32 + w*8 + (l>>3),
    // in-row byte X = (l&7)*16. Source pre-swizzled: X ^= ((r&7)<<4), r&7 == l>>3.
    int srow = w * 8 + (l >> 3);
    unsigned xswz = ((unsigned)((l & 7) * 16)) ^ (((unsigned)(l >> 3)) << 4);
    const char* gA = (const char*)(A + (size_t)(m0 + srow) * K) + xswz;
    const char* gB = (const char*)(W + (size_t)(n0 + srow) * K) + xswz;

    float bias_reg[4];
#pragma unroll
    for (int ni = 0; ni < 4; ++ni) bias_reg[ni] = bias[n0 + wc * 64 + ni * 16 + lo];

    unsigned xm = ((unsigned)(lo & 7)) << 4;   // read-side XOR (row&7 == lo&7)
    f32x4 acc[4][4] = {};
    for (int k0 = 0; k0 < K; k0 += 64) {
#pragma unroll
        for (int c = 0; c < 4; ++c) {
            gload_lds16(gA + ((size_t)(32 * c) * K + k0) * 2, smem + c * 4096 + w * 1024);
            gload_lds16(gB + ((size_t)(32 * c) * K + k0) * 2, smem + 16384 + c * 4096 + w * 1024);
        }
        __syncthreads();
#pragma unroll
        for (int ks = 0; ks < 2; ++ks) {
            bf16x8 af[4], bq[4];
#pragma unroll
            for (int mi = 0; mi < 4; ++mi) {
                int row = wr * 64 + mi * 16 + lo;
                af[mi] = *(const bf16x8*)(smem + row * 128
                          + (((unsigned)(ks * 64 + hi * 16)) ^ xm));
            }
#pragma unroll
            for (int ni = 0; ni < 4; ++ni) {
                int row = wc * 64 + ni * 16 + lo;
                bq[ni] = *(const bf16x8*)(smem + 16384 + row * 128
                          + (((unsigned)(ks * 64 + hi * 16)) ^ xm));
            }
#pragma unroll
            for (int mi = 0; mi < 4; ++mi)
#pragma unroll
                for (int ni = 0; ni < 4; ++ni)
                    acc[mi][ni] = MFMA16(af[mi], bq[ni], acc[mi][ni]);
        }
        __syncthreads();
    }

    // ---- epilogue (v17): wave's 64x64 quadrant -> ONE (head, part); 16B coalesced stores ----
    int q64 = (n0 >> 6) + wc;
    int head = q64 / 3, part = q64 - head * 3;
    int mbase = m0 + wr * 64;
    size_t bh = (size_t)((mbase >> 10) * 8 + head);
    int sbase = mbase & 1023;

    if (part < 2) {
        float scale = (part == 0) ? 0.180336881f : 1.0f;   // 0.125*log2e on q
        __bf16* dst = (part == 0 ? q_ws : k_ws) + (bh * 1024 + sbase) * 64;
        __bf16 (*Ep)[68] = (__bf16 (*)[68])(smem + w * 4352);  // [32 s][64 d +4]
#pragma unroll
        for (int hh = 0; hh < 2; ++hh) {
#pragma unroll
            for (int mi2 = 0; mi2 < 2; ++mi2) {
                int mi = hh * 2 + mi2;
#pragma unroll
                for (int ni = 0; ni < 4; ++ni)
#pragma unroll
                    for (int j = 0; j < 4; ++j)
                        Ep[mi2 * 16 + hi * 4 + j][ni * 16 + lo] =
                            (__bf16)((acc[mi][ni][j] + bias_reg[ni]) * scale);
            }
#pragma unroll
            for (int it = 0; it < 4; ++it) {
                int r = it * 8 + (l >> 3);
                bf16x8 v = *(const bf16x8*)&Ep[r][(l & 7) * 8];
                *(bf16x8*)&dst[(size_t)(hh * 32 + r) * 64 + (l & 7) * 8] = v;
            }
        }
    } else {
        __bf16* dst = vt_ws + bh * 65536 + sbase;            // [d][s] layout
        __bf16 (*Ep)[34] = (__bf16 (*)[34])(smem + w * 4352); // [64 d][32 s +2]
#pragma unroll
        for (int hh = 0; hh < 2; ++hh) {
#pragma unroll
            for (int mi2 = 0; mi2 < 2; ++mi2) {
                int mi = hh * 2 + mi2;
#pragma unroll
                for (int ni = 0; ni < 4; ++ni)
#pragma unroll
                    for (int j = 0; j < 4; ++j)
                        Ep[ni * 16 + lo][mi2 * 16 + hi * 4 + j] =
                            (__bf16)(acc[mi][ni][j] + bias_reg[ni]);
            }
#pragma unroll
            for (int it = 0; it < 4; ++it) {
                int d = it * 16 + (l >> 2);
                bf16x8 v = *(const bf16x8*)&Ep[d][(l & 3) * 8];
                *(bf16x8*)&dst[(size_t)d * 1024 + hh * 32 + (l & 3) * 8] = v;
            }
        }
    }
}

// ---------------- fused attention v15: v10 structure, exp2 softmax ----------------
__global__ __launch_bounds__(256, 4) void k_attn(
    const __bf16* __restrict__ q_ws, const __bf16* __restrict__ k_ws,
    const __bf16* __restrict__ vt_ws,
    float* __restrict__ att_out, __bf16* __restrict__ values)
{
    __shared__ __align__(16) __bf16 Klds[2][64][76];     // 19,456 B
    __shared__ __align__(16) __bf16 Pl[2][4][16][76];    // 19,456 B -> 38 KB, 4 blk/CU

    int bid = blockIdx.x;                    // grid = 1024 (64 bh x 16 q-tiles of 64 rows)
    int nid = (bid & 7) * 128 + (bid >> 3);  // bijective XCD swizzle
    int bh = nid >> 4, qt = nid & 15;
    int t = threadIdx.x, w = t >> 6, l = t & 63;
    int lo = l & 15, hi = l >> 4;
    int q0 = qt * 64 + w * 16;               // wave owns 16 FULL rows

    const __bf16* Qg = q_ws + ((size_t)bh * 1024 + q0 + lo) * 64 + hi * 8;
    bf16x8 qa0 = *(const bf16x8*)Qg;
    bf16x8 qa1 = *(const bf16x8*)(Qg + 32);

    const __bf16* Kb = k_ws + (size_t)bh * 65536;
    int srow = t >> 2, scol = (t & 3) * 16;
    const __bf16* gK = Kb + (size_t)srow * 64 + scol;
    bf16x8 r0, r1;

#define STAGE_LOAD(c)  { const __bf16* p_ = gK + (size_t)(c) * 4096; \
                         r0 = *(const bf16x8*)p_; r1 = *(const bf16x8*)(p_ + 8); }
#define STAGE_WRITE(b) { *(bf16x8*)&Klds[b][srow][scol] = r0; \
                         *(bf16x8*)&Klds[b][srow][scol + 8] = r1; }
#define SCHUNK(b, s)   _Pragma("unroll") \
                       for (int kk = 0; kk < 4; ++kk) { \
                           bf16x8 kb0 = *(const bf16x8*)&Klds[b][kk * 16 + lo][hi * 8]; \
                           bf16x8 kb1 = *(const bf16x8*)&Klds[b][kk * 16 + lo][hi * 8 + 32]; \
                           f32x4 a_ = {}; \
                           a_ = MFMA16(qa0, kb0, a_); \
                           a_ = MFMA16(qa1, kb1, a_); \
                           s[kk] = a_; \
                       }

    // ---- pass A: online (max, sum) per lane; base-2 ----
    f32x4 lmx = { -3.4e38f, -3.4e38f, -3.4e38f, -3.4e38f };
    f32x4 lsum = {};
    STAGE_LOAD(0); STAGE_WRITE(0);
    __syncthreads();
    for (int c = 0; c < 16; ++c) {
        if (c < 15) STAGE_LOAD(c + 1);
        f32x4 s[4];
        SCHUNK(c & 1, s);
#pragma unroll
        for (int j = 0; j < 4; ++j) {
            float cm = fmaxf(fmaxf(s[0][j], s[1][j]), fmaxf(s[2][j], s[3][j]));
            float nm = fmaxf(lmx[j], cm);
            float a = fexp2(s[0][j] - nm) + fexp2(s[1][j] - nm)
                    + fexp2(s[2][j] - nm) + fexp2(s[3][j] - nm);
            lsum[j] = lsum[j] * fexp2(lmx[j] - nm) + a;
            lmx[j] = nm;
        }
        if (c < 15) STAGE_WRITE((c + 1) & 1);
        __syncthreads();
    }
    f32x4 gmx = lmx;
#pragma unroll
    for (int off = 1; off < 16; off <<= 1)
#pragma unroll
        for (int j = 0; j < 4; ++j) gmx[j] = fmaxf(gmx[j], __shfl_xor(gmx[j], off));
    f32x4 part;
#pragma unroll
    for (int j = 0; j < 4; ++j) part[j] = lsum[j] * fexp2(lmx[j] - gmx[j]);
#pragma unroll
    for (int off = 1; off < 16; off <<= 1)
#pragma unroll
        for (int j = 0; j < 4; ++j) part[j] += __shfl_xor(part[j], off);
    f32x4 ginv;
#pragma unroll
    for (int j = 0; j < 4; ++j) ginv[j] = 1.f / part[j];

    // ---- pass B: recompute S, emit att (f32), Pl bf16; PV lagged 1 chunk, d-split ----
    float* gattW = att_out + ((size_t)bh * 1024 + q0) * 1024;
    const __bf16* Vb = vt_ws + (size_t)bh * 65536 + (size_t)(w * 16 + lo) * 1024 + hi * 8;
    f32x4 oacc[4] = {};

    STAGE_LOAD(0); STAGE_WRITE(0);
    __syncthreads();
    for (int c = 0; c < 16; ++c) {
        if (c < 15) STAGE_LOAD(c + 1);
        f32x4 s[4];
        SCHUNK(c & 1, s);
#pragma unroll
        for (int kk = 0; kk < 4; ++kk)
#pragma unroll
            for (int j = 0; j < 4; ++j) {
                float p = fexp2(s[kk][j] - gmx[j]) * ginv[j];
                gattW[(size_t)(hi * 4 + j) * 1024 + c * 64 + kk * 16 + lo] = p;
                Pl[c & 1][w][hi * 4 + j][kk * 16 + lo] = (__bf16)p;
            }
        if (c > 0) {   // PV for chunk c-1
            int pb = (c - 1) & 1;
            const __bf16* vp = Vb + (size_t)(c - 1) * 64;
            bf16x8 vb0 = *(const bf16x8*)vp;
            bf16x8 vb1 = *(const bf16x8*)(vp + 32);
#pragma unroll
            for (int g = 0; g < 4; ++g) {
                bf16x8 pa0 = *(const bf16x8*)&Pl[pb][g][lo][hi * 8];
                bf16x8 pa1 = *(const bf16x8*)&Pl[pb][g][lo][hi * 8 + 32];
                oacc[g] = MFMA16(pa0, vb0, oacc[g]);
                oacc[g] = MFMA16(pa1, vb1, oacc[g]);
            }
        }
        if (c < 15) STAGE_WRITE((c + 1) & 1);
        __syncthreads();
    }
    {   // final PV: chunk 15
        const __bf16* vp = Vb + (size_t)15 * 64;
        bf16x8 vb0 = *(const bf16x8*)vp;
        bf16x8 vb1 = *(const bf16x8*)(vp + 32);
#pragma unroll
        for (int g = 0; g < 4; ++g) {
            bf16x8 pa0 = *(const bf16x8*)&Pl[1][g][lo][hi * 8];
            bf16x8 pa1 = *(const bf16x8*)&Pl[1][g][lo][hi * 8 + 32];
            oacc[g] = MFMA16(pa0, vb0, oacc[g]);
            oacc[g] = MFMA16(pa1, vb1, oacc[g]);
        }
    }

    int b = bh >> 3, h = bh & 7;
#pragma unroll
    for (int g = 0; g < 4; ++g)
#pragma unroll
        for (int j = 0; j < 4; ++j)
            values[((size_t)b * 1024 + qt * 64 + g * 16 + hi * 4 + j) * 512
                   + h * 64 + w * 16 + lo] = (__bf16)oacc[g][j];
#undef STAGE_LOAD
#undef STAGE_WRITE
#undef SCHUNK
}

// ---------------- output GEMM (m97 structure) ----------------
__global__ __launch_bounds__(256) void k_out_gemm(
    const __bf16* __restrict__ A, const __bf16* __restrict__ W,
    const float* __restrict__ bias, float* __restrict__ out)
{
    const int K = 512;
    __shared__ __align__(16) __bf16 As[128][32];
    __shared__ __align__(16) __bf16 Bs[128][32];
    int m0 = blockIdx.x * 128, n0 = blockIdx.y * 128;
    int t = threadIdx.x, w = t >> 6, l = t & 63;
    int lo = l & 15, hi = l >> 4;
    int wr = w >> 1, wc = w & 1;

    const __bf16* gA = A + (size_t)(m0 + w * 16 + (l >> 2)) * K + (l & 3) * 8;
    const __bf16* gB = W + (size_t)(n0 + w * 16 + (l >> 2)) * K + (l & 3) * 8;
    char* lA = (char*)&As[0][0] + w * 1024;
    char* lB = (char*)&Bs[0][0] + w * 1024;

    f32x4 acc[4][4] = {};
    for (int k0 = 0; k0 < K; k0 += 32) {
        gload_lds16(gA + k0, lA);
        gload_lds16(gA + 64 * K + k0, lA + 4096);
        gload_lds16(gB + k0, lB);
        gload_lds16(gB + 64 * K + k0, lB + 4096);
        __syncthreads();
        bf16x8 af[4], bq[4];
#pragma unroll
        for (int mi = 0; mi < 4; ++mi) af[mi] = *(const bf16x8*)&As[wr * 64 + mi * 16 + lo][hi * 8];
#pragma unroll
        for (int ni = 0; ni < 4; ++ni) bq[ni] = *(const bf16x8*)&Bs[wc * 64 + ni * 16 + lo][hi * 8];
#pragma unroll
        for (int mi = 0; mi < 4; ++mi)
#pragma unroll
            for (int ni = 0; ni < 4; ++ni)
                acc[mi][ni] = MFMA16(af[mi], bq[ni], acc[mi][ni]);
        __syncthreads();
    }

#pragma unroll
    for (int ni = 0; ni < 4; ++ni) {
        int n = n0 + wc * 64 + ni * 16 + lo;
        float bn = bias[n];
#pragma unroll
        for (int mi = 0; mi < 4; ++mi)
#pragma unroll
            for (int j = 0; j < 4; ++j) {
                int m = m0 + wr * 64 + mi * 16 + hi * 4 + j;
                out[(size_t)m * 512 + n] = acc[mi][ni][j] + bn;
            }
    }
}

extern "C" void kernel_launch(void* const* d_in, const int* in_sizes, int n_in,
                              void* d_out, int out_size, void* d_ws, size_t ws_size,
                              hipStream_t stream)
{
    const float* x    = (const float*)d_in[0];
    const float* inp  = (const float*)d_in[1];
    const float* Wqkv = (const float*)d_in[2];
    const float* bqkv = (const float*)d_in[3];
    const float* Wo   = (const float*)d_in[4];
    const float* bo   = (const float*)d_in[5];

    float* out_o   = (float*)d_out;
    float* out_att = out_o + (size_t)8 * 1024 * 512;

    char* ws = (char*)d_ws;
    __bf16* xc    = (__bf16*)(ws + 0);
    __bf16* wq    = (__bf16*)(ws + 9437184);
    __bf16* wo    = (__bf16*)(ws + 11206656);
    __bf16* q_ws  = (__bf16*)(ws + 11730944);
    __bf16* k_ws  = (__bf16*)(ws + 20119552);
    __bf16* vt_ws = (__bf16*)(ws + 28508160);
    __bf16* vals  = (__bf16*)(ws + 36896768);

    k_convert<<<2864, 256, 0, stream>>>(x, inp, Wqkv, Wo, xc, wq, wo);
    k_qkv_gemm<<<dim3(64, 12), 256, 0, stream>>>(xc, wq, bqkv, q_ws, k_ws, vt_ws);
    k_attn<<<1024, 256, 0, stream>>>(q_ws, k_ws, vt_ws, out_att, vals);
    k_out_gemm<<<dim3(64, 4), 256, 0, stream>>>(vals, wo, bo, out_o);
}

// Round 20
// 124.355 us; speedup vs baseline: 1.0485x; 1.0485x over previous
//
#include <hip/hip_runtime.h>

typedef __bf16 bf16x8 __attribute__((ext_vector_type(8)));
typedef __bf16 bf16x4 __attribute__((ext_vector_type(4)));
typedef float f32x4 __attribute__((ext_vector_type(4)));

#define MFMA16(a,b,c) __builtin_amdgcn_mfma_f32_16x16x32_bf16((a),(b),(c),0,0,0)

__device__ __forceinline__ float fexp2(float x) { return __builtin_amdgcn_exp2f(x); }

__device__ __forceinline__ void gload_lds16(const void* g, void* l) {
    __builtin_amdgcn_global_load_lds(
        (const __attribute__((address_space(1))) void*)g,
        (__attribute__((address_space(3))) void*)l, 16, 0, 0);
}

// Problem constants: B=8 S=1024 IN=512 ORIG=64 E=512 H=8 hd=64
// q pre-scaled by 0.125*log2(e): softmax in base-2

__global__ __launch_bounds__(256) void k_convert(
    const float* __restrict__ x, const float* __restrict__ inp,
    const float* __restrict__ Wqkv, const float* __restrict__ Wo,
    __bf16* __restrict__ xc, __bf16* __restrict__ wq, __bf16* __restrict__ wo)
{
    const unsigned C1 = 589824u;
    const unsigned C2 = 110592u;
    unsigned i = blockIdx.x * 256u + threadIdx.x;
    if (i < C1) {
        unsigned e = i * 8u;
        unsigned m = e / 576u, k = e - m * 576u;
        const float* p = (k < 512u) ? x + (size_t)m * 512u + k
                                    : inp + (size_t)m * 64u + (k - 512u);
        f32x4 a = *(const f32x4*)p, b = *(const f32x4*)(p + 4);
        bf16x8 o;
#pragma unroll
        for (int j = 0; j < 4; ++j) { o[j] = (__bf16)a[j]; o[j + 4] = (__bf16)b[j]; }
        *(bf16x8*)&xc[e] = o;
    } else if (i < C1 + C2) {
        unsigned e = (i - C1) * 8u;
        f32x4 a = *(const f32x4*)&Wqkv[e], b = *(const f32x4*)&Wqkv[e + 4];
        bf16x8 o;
#pragma unroll
        for (int j = 0; j < 4; ++j) { o[j] = (__bf16)a[j]; o[j + 4] = (__bf16)b[j]; }
        *(bf16x8*)&wq[e] = o;
    } else {
        unsigned e = (i - C1 - C2) * 8u;
        f32x4 a = *(const f32x4*)&Wo[e], b = *(const f32x4*)&Wo[e + 4];
        bf16x8 o;
#pragma unroll
        for (int j = 0; j < 4; ++j) { o[j] = (__bf16)a[j]; o[j + 4] = (__bf16)b[j]; }
        *(bf16x8*)&wo[e] = o;
    }
}

// ---------------- QKV GEMM v2 (v17, best): m97 K-loop BK=32 + wave-uniform coalesced epilogue ----------------
__global__ __launch_bounds__(256) void k_qkv_gemm(
    const __bf16* __restrict__ A, const __bf16* __restrict__ W,
    const float* __restrict__ bias,
    __bf16* __restrict__ q_ws, __bf16* __restrict__ k_ws, __bf16* __restrict__ vt_ws)
{
    const int K = 576;
    __shared__ __align__(16) char smem[17408];   // As 8K | Bs 8K ; epilogue reuses as 4x4352B
    __bf16 (*As)[32] = (__bf16 (*)[32])smem;
    __bf16 (*Bs)[32] = (__bf16 (*)[32])(smem + 8192);
    int m0 = blockIdx.x * 128, n0 = blockIdx.y * 128;
    int t = threadIdx.x, w = t >> 6, l = t & 63;
    int lo = l & 15, hi = l >> 4;
    int wr = w >> 1, wc = w & 1;

    const __bf16* gA = A + (size_t)(m0 + w * 16 + (l >> 2)) * K + (l & 3) * 8;
    const __bf16* gB = W + (size_t)(n0 + w * 16 + (l >> 2)) * K + (l & 3) * 8;
    char* lA = smem + w * 1024;
    char* lB = smem + 8192 + w * 1024;

    float bias_reg[4];
#pragma unroll
    for (int ni = 0; ni < 4; ++ni) bias_reg[ni] = bias[n0 + wc * 64 + ni * 16 + lo];

    f32x4 acc[4][4] = {};
    for (int k0 = 0; k0 < K; k0 += 32) {
        gload_lds16(gA + k0, lA);
        gload_lds16(gA + 64 * K + k0, lA + 4096);
        gload_lds16(gB + k0, lB);
        gload_lds16(gB + 64 * K + k0, lB + 4096);
        __syncthreads();
        bf16x8 af[4], bq[4];
#pragma unroll
        for (int mi = 0; mi < 4; ++mi) af[mi] = *(const bf16x8*)&As[wr * 64 + mi * 16 + lo][hi * 8];
#pragma unroll
        for (int ni = 0; ni < 4; ++ni) bq[ni] = *(const bf16x8*)&Bs[wc * 64 + ni * 16 + lo][hi * 8];
#pragma unroll
        for (int mi = 0; mi < 4; ++mi)
#pragma unroll
            for (int ni = 0; ni < 4; ++ni)
                acc[mi][ni] = MFMA16(af[mi], bq[ni], acc[mi][ni]);
        __syncthreads();
    }

    int q64 = (n0 >> 6) + wc;
    int head = q64 / 3, part = q64 - head * 3;
    int mbase = m0 + wr * 64;
    size_t bh = (size_t)((mbase >> 10) * 8 + head);
    int sbase = mbase & 1023;

    if (part < 2) {
        float scale = (part == 0) ? 0.180336881f : 1.0f;   // 0.125*log2e on q
        __bf16* dst = (part == 0 ? q_ws : k_ws) + (bh * 1024 + sbase) * 64;
        __bf16 (*Ep)[68] = (__bf16 (*)[68])(smem + w * 4352);
#pragma unroll
        for (int hh = 0; hh < 2; ++hh) {
#pragma unroll
            for (int mi2 = 0; mi2 < 2; ++mi2) {
                int mi = hh * 2 + mi2;
#pragma unroll
                for (int ni = 0; ni < 4; ++ni)
#pragma unroll
                    for (int j = 0; j < 4; ++j)
                        Ep[mi2 * 16 + hi * 4 + j][ni * 16 + lo] =
                            (__bf16)((acc[mi][ni][j] + bias_reg[ni]) * scale);
            }
#pragma unroll
            for (int it = 0; it < 4; ++it) {
                int r = it * 8 + (l >> 3);
                bf16x8 v = *(const bf16x8*)&Ep[r][(l & 7) * 8];
                *(bf16x8*)&dst[(size_t)(hh * 32 + r) * 64 + (l & 7) * 8] = v;
            }
        }
    } else {
        __bf16* dst = vt_ws + bh * 65536 + sbase;
        __bf16 (*Ep)[34] = (__bf16 (*)[34])(smem + w * 4352);
#pragma unroll
        for (int hh = 0; hh < 2; ++hh) {
#pragma unroll
            for (int mi2 = 0; mi2 < 2; ++mi2) {
                int mi = hh * 2 + mi2;
#pragma unroll
                for (int ni = 0; ni < 4; ++ni)
#pragma unroll
                    for (int j = 0; j < 4; ++j)
                        Ep[ni * 16 + lo][mi2 * 16 + hi * 4 + j] =
                            (__bf16)(acc[mi][ni][j] + bias_reg[ni]);
            }
#pragma unroll
            for (int it = 0; it < 4; ++it) {
                int d = it * 16 + (l >> 2);
                bf16x8 v = *(const bf16x8*)&Ep[d][(l & 3) * 8];
                *(bf16x8*)&dst[(size_t)d * 1024 + hh * 32 + (l & 3) * 8] = v;
            }
        }
    }
}

// ---------------- fused attention v15: v10 structure, exp2 softmax ----------------
__global__ __launch_bounds__(256, 4) void k_attn(
    const __bf16* __restrict__ q_ws, const __bf16* __restrict__ k_ws,
    const __bf16* __restrict__ vt_ws,
    float* __restrict__ att_out, __bf16* __restrict__ values)
{
    __shared__ __align__(16) __bf16 Klds[2][64][76];
    __shared__ __align__(16) __bf16 Pl[2][4][16][76];

    int bid = blockIdx.x;
    int nid = (bid & 7) * 128 + (bid >> 3);
    int bh = nid >> 4, qt = nid & 15;
    int t = threadIdx.x, w = t >> 6, l = t & 63;
    int lo = l & 15, hi = l >> 4;
    int q0 = qt * 64 + w * 16;

    const __bf16* Qg = q_ws + ((size_t)bh * 1024 + q0 + lo) * 64 + hi * 8;
    bf16x8 qa0 = *(const bf16x8*)Qg;
    bf16x8 qa1 = *(const bf16x8*)(Qg + 32);

    const __bf16* Kb = k_ws + (size_t)bh * 65536;
    int srow = t >> 2, scol = (t & 3) * 16;
    const __bf16* gK = Kb + (size_t)srow * 64 + scol;
    bf16x8 r0, r1;

#define STAGE_LOAD(c)  { const __bf16* p_ = gK + (size_t)(c) * 4096; \
                         r0 = *(const bf16x8*)p_; r1 = *(const bf16x8*)(p_ + 8); }
#define STAGE_WRITE(b) { *(bf16x8*)&Klds[b][srow][scol] = r0; \
                         *(bf16x8*)&Klds[b][srow][scol + 8] = r1; }
#define SCHUNK(b, s)   _Pragma("unroll") \
                       for (int kk = 0; kk < 4; ++kk) { \
                           bf16x8 kb0 = *(const bf16x8*)&Klds[b][kk * 16 + lo][hi * 8]; \
                           bf16x8 kb1 = *(const bf16x8*)&Klds[b][kk * 16 + lo][hi * 8 + 32]; \
                           f32x4 a_ = {}; \
                           a_ = MFMA16(qa0, kb0, a_); \
                           a_ = MFMA16(qa1, kb1, a_); \
                           s[kk] = a_; \
                       }

    // ---- pass A: online (max, sum) per lane; base-2 ----
    f32x4 lmx = { -3.4e38f, -3.4e38f, -3.4e38f, -3.4e38f };
    f32x4 lsum = {};
    STAGE_LOAD(0); STAGE_WRITE(0);
    __syncthreads();
    for (int c = 0; c < 16; ++c) {
        if (c < 15) STAGE_LOAD(c + 1);
        f32x4 s[4];
        SCHUNK(c & 1, s);
#pragma unroll
        for (int j = 0; j < 4; ++j) {
            float cm = fmaxf(fmaxf(s[0][j], s[1][j]), fmaxf(s[2][j], s[3][j]));
            float nm = fmaxf(lmx[j], cm);
            float a = fexp2(s[0][j] - nm) + fexp2(s[1][j] - nm)
                    + fexp2(s[2][j] - nm) + fexp2(s[3][j] - nm);
            lsum[j] = lsum[j] * fexp2(lmx[j] - nm) + a;
            lmx[j] = nm;
        }
        if (c < 15) STAGE_WRITE((c + 1) & 1);
        __syncthreads();
    }
    f32x4 gmx = lmx;
#pragma unroll
    for (int off = 1; off < 16; off <<= 1)
#pragma unroll
        for (int j = 0; j < 4; ++j) gmx[j] = fmaxf(gmx[j], __shfl_xor(gmx[j], off));
    f32x4 part;
#pragma unroll
    for (int j = 0; j < 4; ++j) part[j] = lsum[j] * fexp2(lmx[j] - gmx[j]);
#pragma unroll
    for (int off = 1; off < 16; off <<= 1)
#pragma unroll
        for (int j = 0; j < 4; ++j) part[j] += __shfl_xor(part[j], off);
    f32x4 ginv;
#pragma unroll
    for (int j = 0; j < 4; ++j) ginv[j] = 1.f / part[j];

    // ---- pass B: recompute S, emit att (f32), Pl bf16; PV lagged 1 chunk, d-split ----
    float* gattW = att_out + ((size_t)bh * 1024 + q0) * 1024;
    const __bf16* Vb = vt_ws + (size_t)bh * 65536 + (size_t)(w * 16 + lo) * 1024 + hi * 8;
    f32x4 oacc[4] = {};

    STAGE_LOAD(0); STAGE_WRITE(0);
    __syncthreads();
    for (int c = 0; c < 16; ++c) {
        if (c < 15) STAGE_LOAD(c + 1);
        f32x4 s[4];
        SCHUNK(c & 1, s);
#pragma unroll
        for (int kk = 0; kk < 4; ++kk)
#pragma unroll
            for (int j = 0; j < 4; ++j) {
                float p = fexp2(s[kk][j] - gmx[j]) * ginv[j];
                gattW[(size_t)(hi * 4 + j) * 1024 + c * 64 + kk * 16 + lo] = p;
                Pl[c & 1][w][hi * 4 + j][kk * 16 + lo] = (__bf16)p;
            }
        if (c > 0) {
            int pb = (c - 1) & 1;
            const __bf16* vp = Vb + (size_t)(c - 1) * 64;
            bf16x8 vb0 = *(const bf16x8*)vp;
            bf16x8 vb1 = *(const bf16x8*)(vp + 32);
#pragma unroll
            for (int g = 0; g < 4; ++g) {
                bf16x8 pa0 = *(const bf16x8*)&Pl[pb][g][lo][hi * 8];
                bf16x8 pa1 = *(const bf16x8*)&Pl[pb][g][lo][hi * 8 + 32];
                oacc[g] = MFMA16(pa0, vb0, oacc[g]);
                oacc[g] = MFMA16(pa1, vb1, oacc[g]);
            }
        }
        if (c < 15) STAGE_WRITE((c + 1) & 1);
        __syncthreads();
    }
    {
        const __bf16* vp = Vb + (size_t)15 * 64;
        bf16x8 vb0 = *(const bf16x8*)vp;
        bf16x8 vb1 = *(const bf16x8*)(vp + 32);
#pragma unroll
        for (int g = 0; g < 4; ++g) {
            bf16x8 pa0 = *(const bf16x8*)&Pl[1][g][lo][hi * 8];
            bf16x8 pa1 = *(const bf16x8*)&Pl[1][g][lo][hi * 8 + 32];
            oacc[g] = MFMA16(pa0, vb0, oacc[g]);
            oacc[g] = MFMA16(pa1, vb1, oacc[g]);
        }
    }

    int b = bh >> 3, h = bh & 7;
#pragma unroll
    for (int g = 0; g < 4; ++g)
#pragma unroll
        for (int j = 0; j < 4; ++j)
            values[((size_t)b * 1024 + qt * 64 + g * 16 + hi * 4 + j) * 512
                   + h * 64 + w * 16 + lo] = (__bf16)oacc[g][j];
#undef STAGE_LOAD
#undef STAGE_WRITE
#undef SCHUNK
}

// ---------------- output GEMM v2: 128x64 tile, 512 blocks (2/CU) ----------------
__global__ __launch_bounds__(256) void k_out_gemm(
    const __bf16* __restrict__ A, const __bf16* __restrict__ W,
    const float* __restrict__ bias, float* __restrict__ out)
{
    const int K = 512;
    __shared__ __align__(16) __bf16 As[128][32];   // 8 KB
    __shared__ __align__(16) __bf16 Bs[64][32];    // 4 KB
    int m0 = blockIdx.x * 128, n0 = blockIdx.y * 64;
    int t = threadIdx.x, w = t >> 6, l = t & 63;
    int lo = l & 15, hi = l >> 4;

    // staging maps: As 8KB -> 2x16B/thread; Bs 4KB -> 1x16B/thread
    const __bf16* gA0 = A + (size_t)(m0 + (t >> 2)) * K + (t & 3) * 8;
    const __bf16* gA1 = A + (size_t)(m0 + 64 + (t >> 2)) * K + (t & 3) * 8;
    const __bf16* gB  = W + (size_t)(n0 + (t >> 2)) * K + (t & 3) * 8;
    char* lA0 = (char*)&As[0][0] + t * 16;
    char* lA1 = (char*)&As[64][0] + t * 16;
    char* lB  = (char*)&Bs[0][0] + t * 16;

    f32x4 acc[2][4] = {};
    for (int k0 = 0; k0 < K; k0 += 32) {
        gload_lds16(gA0 + k0, lA0);
        gload_lds16(gA1 + k0, lA1);
        gload_lds16(gB + k0, lB);
        __syncthreads();
        bf16x8 af[2], bq[4];
#pragma unroll
        for (int mi = 0; mi < 2; ++mi) af[mi] = *(const bf16x8*)&As[w * 32 + mi * 16 + lo][hi * 8];
#pragma unroll
        for (int ni = 0; ni < 4; ++ni) bq[ni] = *(const bf16x8*)&Bs[ni * 16 + lo][hi * 8];
#pragma unroll
        for (int mi = 0; mi < 2; ++mi)
#pragma unroll
            for (int ni = 0; ni < 4; ++ni)
                acc[mi][ni] = MFMA16(af[mi], bq[ni], acc[mi][ni]);
        __syncthreads();
    }

#pragma unroll
    for (int ni = 0; ni < 4; ++ni) {
        int n = n0 + ni * 16 + lo;
        float bn = bias[n];
#pragma unroll
        for (int mi = 0; mi < 2; ++mi)
#pragma unroll
            for (int j = 0; j < 4; ++j) {
                int m = m0 + w * 32 + mi * 16 + hi * 4 + j;
                out[(size_t)m * 512 + n] = acc[mi][ni][j] + bn;
            }
    }
}

extern "C" void kernel_launch(void* const* d_in, const int* in_sizes, int n_in,
                              void* d_out, int out_size, void* d_ws, size_t ws_size,
                              hipStream_t stream)
{
    const float* x    = (const float*)d_in[0];
    const float* inp  = (const float*)d_in[1];
    const float* Wqkv = (const float*)d_in[2];
    const float* bqkv = (const float*)d_in[3];
    const float* Wo   = (const float*)d_in[4];
    const float* bo   = (const float*)d_in[5];

    float* out_o   = (float*)d_out;
    float* out_att = out_o + (size_t)8 * 1024 * 512;

    char* ws = (char*)d_ws;
    __bf16* xc    = (__bf16*)(ws + 0);
    __bf16* wq    = (__bf16*)(ws + 9437184);
    __bf16* wo    = (__bf16*)(ws + 11206656);
    __bf16* q_ws  = (__bf16*)(ws + 11730944);
    __bf16* k_ws  = (__bf16*)(ws + 20119552);
    __bf16* vt_ws = (__bf16*)(ws + 28508160);
    __bf16* vals  = (__bf16*)(ws + 36896768);

    k_convert<<<2864, 256, 0, stream>>>(x, inp, Wqkv, Wo, xc, wq, wo);
    k_qkv_gemm<<<dim3(64, 12), 256, 0, stream>>>(xc, wq, bqkv, q_ws, k_ws, vt_ws);
    k_attn<<<1024, 256, 0, stream>>>(q_ws, k_ws, vt_ws, out_att, vals);
    k_out_gemm<<<dim3(64, 8), 256, 0, stream>>>(vals, wo, bo, out_o);
}

// Round 21
// 123.327 us; speedup vs baseline: 1.0572x; 1.0083x over previous
//
#include <hip/hip_runtime.h>

typedef __bf16 bf16x8 __attribute__((ext_vector_type(8)));
typedef __bf16 bf16x4 __attribute__((ext_vector_type(4)));
typedef float f32x4 __attribute__((ext_vector_type(4)));

#define MFMA16(a,b,c) __builtin_amdgcn_mfma_f32_16x16x32_bf16((a),(b),(c),0,0,0)

__device__ __forceinline__ float fexp2(float x) { return __builtin_amdgcn_exp2f(x); }

__device__ __forceinline__ void gload_lds16(const void* g, void* l) {
    __builtin_amdgcn_global_load_lds(
        (const __attribute__((address_space(1))) void*)g,
        (__attribute__((address_space(3))) void*)l, 16, 0, 0);
}

// Problem constants: B=8 S=1024 IN=512 ORIG=64 E=512 H=8 hd=64
// q pre-scaled by 0.125*log2(e): softmax in base-2

__global__ __launch_bounds__(256) void k_convert(
    const float* __restrict__ x, const float* __restrict__ inp,
    const float* __restrict__ Wqkv, const float* __restrict__ Wo,
    __bf16* __restrict__ xc, __bf16* __restrict__ wq, __bf16* __restrict__ wo)
{
    const unsigned C1 = 589824u;
    const unsigned C2 = 110592u;
    unsigned i = blockIdx.x * 256u + threadIdx.x;
    if (i < C1) {
        unsigned e = i * 8u;
        unsigned m = e / 576u, k = e - m * 576u;
        const float* p = (k < 512u) ? x + (size_t)m * 512u + k
                                    : inp + (size_t)m * 64u + (k - 512u);
        f32x4 a = *(const f32x4*)p, b = *(const f32x4*)(p + 4);
        bf16x8 o;
#pragma unroll
        for (int j = 0; j < 4; ++j) { o[j] = (__bf16)a[j]; o[j + 4] = (__bf16)b[j]; }
        *(bf16x8*)&xc[e] = o;
    } else if (i < C1 + C2) {
        unsigned e = (i - C1) * 8u;
        f32x4 a = *(const f32x4*)&Wqkv[e], b = *(const f32x4*)&Wqkv[e + 4];
        bf16x8 o;
#pragma unroll
        for (int j = 0; j < 4; ++j) { o[j] = (__bf16)a[j]; o[j + 4] = (__bf16)b[j]; }
        *(bf16x8*)&wq[e] = o;
    } else {
        unsigned e = (i - C1 - C2) * 8u;
        f32x4 a = *(const f32x4*)&Wo[e], b = *(const f32x4*)&Wo[e + 4];
        bf16x8 o;
#pragma unroll
        for (int j = 0; j < 4; ++j) { o[j] = (__bf16)a[j]; o[j + 4] = (__bf16)b[j]; }
        *(bf16x8*)&wo[e] = o;
    }
}

// ---------------- QKV GEMM v4: BK=32 + DOUBLE-BUFFERED LDS, one barrier/iter ----------------
__global__ __launch_bounds__(256) void k_qkv_gemm(
    const __bf16* __restrict__ A, const __bf16* __restrict__ W,
    const float* __restrict__ bias,
    __bf16* __restrict__ q_ws, __bf16* __restrict__ k_ws, __bf16* __restrict__ vt_ws)
{
    const int K = 576;
    __shared__ __align__(16) char smem[32768];   // buf0: As@0 Bs@8192 | buf1: As@16384 Bs@24576
    int m0 = blockIdx.x * 128, n0 = blockIdx.y * 128;
    int t = threadIdx.x, w = t >> 6, l = t & 63;
    int lo = l & 15, hi = l >> 4;
    int wr = w >> 1, wc = w & 1;

    const __bf16* gA = A + (size_t)(m0 + w * 16 + (l >> 2)) * K + (l & 3) * 8;
    const __bf16* gB = W + (size_t)(n0 + w * 16 + (l >> 2)) * K + (l & 3) * 8;

    float bias_reg[4];
#pragma unroll
    for (int ni = 0; ni < 4; ++ni) bias_reg[ni] = bias[n0 + wc * 64 + ni * 16 + lo];

#define QSTAGE(k0, buf) { char* lA_ = smem + (buf) * 16384 + w * 1024; \
                          char* lB_ = smem + (buf) * 16384 + 8192 + w * 1024; \
                          gload_lds16(gA + (k0), lA_); \
                          gload_lds16(gA + 64 * K + (k0), lA_ + 4096); \
                          gload_lds16(gB + (k0), lB_); \
                          gload_lds16(gB + 64 * K + (k0), lB_ + 4096); }

    f32x4 acc[4][4] = {};
    QSTAGE(0, 0);
    __syncthreads();
    for (int it = 0; it < 18; ++it) {
        if (it < 17) QSTAGE((it + 1) * 32, (it + 1) & 1);
        const __bf16 (*As)[32] = (const __bf16 (*)[32])(smem + (it & 1) * 16384);
        const __bf16 (*Bs)[32] = (const __bf16 (*)[32])(smem + (it & 1) * 16384 + 8192);
        bf16x8 af[4], bq[4];
#pragma unroll
        for (int mi = 0; mi < 4; ++mi) af[mi] = *(const bf16x8*)&As[wr * 64 + mi * 16 + lo][hi * 8];
#pragma unroll
        for (int ni = 0; ni < 4; ++ni) bq[ni] = *(const bf16x8*)&Bs[wc * 64 + ni * 16 + lo][hi * 8];
#pragma unroll
        for (int mi = 0; mi < 4; ++mi)
#pragma unroll
            for (int ni = 0; ni < 4; ++ni)
                acc[mi][ni] = MFMA16(af[mi], bq[ni], acc[mi][ni]);
        __syncthreads();   // drains prefetch + fences buffer reuse (1 barrier/iter)
    }
#undef QSTAGE

    int q64 = (n0 >> 6) + wc;
    int head = q64 / 3, part = q64 - head * 3;
    int mbase = m0 + wr * 64;
    size_t bh = (size_t)((mbase >> 10) * 8 + head);
    int sbase = mbase & 1023;

    if (part < 2) {
        float scale = (part == 0) ? 0.180336881f : 1.0f;   // 0.125*log2e on q
        __bf16* dst = (part == 0 ? q_ws : k_ws) + (bh * 1024 + sbase) * 64;
        __bf16 (*Ep)[68] = (__bf16 (*)[68])(smem + w * 4352);
#pragma unroll
        for (int hh = 0; hh < 2; ++hh) {
#pragma unroll
            for (int mi2 = 0; mi2 < 2; ++mi2) {
                int mi = hh * 2 + mi2;
#pragma unroll
                for (int ni = 0; ni < 4; ++ni)
#pragma unroll
                    for (int j = 0; j < 4; ++j)
                        Ep[mi2 * 16 + hi * 4 + j][ni * 16 + lo] =
                            (__bf16)((acc[mi][ni][j] + bias_reg[ni]) * scale);
            }
#pragma unroll
            for (int it = 0; it < 4; ++it) {
                int r = it * 8 + (l >> 3);
                bf16x8 v = *(const bf16x8*)&Ep[r][(l & 7) * 8];
                *(bf16x8*)&dst[(size_t)(hh * 32 + r) * 64 + (l & 7) * 8] = v;
            }
        }
    } else {
        __bf16* dst = vt_ws + bh * 65536 + sbase;
        __bf16 (*Ep)[34] = (__bf16 (*)[34])(smem + w * 4352);
#pragma unroll
        for (int hh = 0; hh < 2; ++hh) {
#pragma unroll
            for (int mi2 = 0; mi2 < 2; ++mi2) {
                int mi = hh * 2 + mi2;
#pragma unroll
                for (int ni = 0; ni < 4; ++ni)
#pragma unroll
                    for (int j = 0; j < 4; ++j)
                        Ep[ni * 16 + lo][mi2 * 16 + hi * 4 + j] =
                            (__bf16)(acc[mi][ni][j] + bias_reg[ni]);
            }
#pragma unroll
            for (int it = 0; it < 4; ++it) {
                int d = it * 16 + (l >> 2);
                bf16x8 v = *(const bf16x8*)&Ep[d][(l & 3) * 8];
                *(bf16x8*)&dst[(size_t)d * 1024 + hh * 32 + (l & 3) * 8] = v;
            }
        }
    }
}

// ---------------- fused attention v15: v10 structure, exp2 softmax ----------------
__global__ __launch_bounds__(256, 4) void k_attn(
    const __bf16* __restrict__ q_ws, const __bf16* __restrict__ k_ws,
    const __bf16* __restrict__ vt_ws,
    float* __restrict__ att_out, __bf16* __restrict__ values)
{
    __shared__ __align__(16) __bf16 Klds[2][64][76];
    __shared__ __align__(16) __bf16 Pl[2][4][16][76];

    int bid = blockIdx.x;
    int nid = (bid & 7) * 128 + (bid >> 3);
    int bh = nid >> 4, qt = nid & 15;
    int t = threadIdx.x, w = t >> 6, l = t & 63;
    int lo = l & 15, hi = l >> 4;
    int q0 = qt * 64 + w * 16;

    const __bf16* Qg = q_ws + ((size_t)bh * 1024 + q0 + lo) * 64 + hi * 8;
    bf16x8 qa0 = *(const bf16x8*)Qg;
    bf16x8 qa1 = *(const bf16x8*)(Qg + 32);

    const __bf16* Kb = k_ws + (size_t)bh * 65536;
    int srow = t >> 2, scol = (t & 3) * 16;
    const __bf16* gK = Kb + (size_t)srow * 64 + scol;
    bf16x8 r0, r1;

#define STAGE_LOAD(c)  { const __bf16* p_ = gK + (size_t)(c) * 4096; \
                         r0 = *(const bf16x8*)p_; r1 = *(const bf16x8*)(p_ + 8); }
#define STAGE_WRITE(b) { *(bf16x8*)&Klds[b][srow][scol] = r0; \
                         *(bf16x8*)&Klds[b][srow][scol + 8] = r1; }
#define SCHUNK(b, s)   _Pragma("unroll") \
                       for (int kk = 0; kk < 4; ++kk) { \
                           bf16x8 kb0 = *(const bf16x8*)&Klds[b][kk * 16 + lo][hi * 8]; \
                           bf16x8 kb1 = *(const bf16x8*)&Klds[b][kk * 16 + lo][hi * 8 + 32]; \
                           f32x4 a_ = {}; \
                           a_ = MFMA16(qa0, kb0, a_); \
                           a_ = MFMA16(qa1, kb1, a_); \
                           s[kk] = a_; \
                       }

    // ---- pass A: online (max, sum) per lane; base-2 ----
    f32x4 lmx = { -3.4e38f, -3.4e38f, -3.4e38f, -3.4e38f };
    f32x4 lsum = {};
    STAGE_LOAD(0); STAGE_WRITE(0);
    __syncthreads();
    for (int c = 0; c < 16; ++c) {
        if (c < 15) STAGE_LOAD(c + 1);
        f32x4 s[4];
        SCHUNK(c & 1, s);
#pragma unroll
        for (int j = 0; j < 4; ++j) {
            float cm = fmaxf(fmaxf(s[0][j], s[1][j]), fmaxf(s[2][j], s[3][j]));
            float nm = fmaxf(lmx[j], cm);
            float a = fexp2(s[0][j] - nm) + fexp2(s[1][j] - nm)
                    + fexp2(s[2][j] - nm) + fexp2(s[3][j] - nm);
            lsum[j] = lsum[j] * fexp2(lmx[j] - nm) + a;
            lmx[j] = nm;
        }
        if (c < 15) STAGE_WRITE((c + 1) & 1);
        __syncthreads();
    }
    f32x4 gmx = lmx;
#pragma unroll
    for (int off = 1; off < 16; off <<= 1)
#pragma unroll
        for (int j = 0; j < 4; ++j) gmx[j] = fmaxf(gmx[j], __shfl_xor(gmx[j], off));
    f32x4 part;
#pragma unroll
    for (int j = 0; j < 4; ++j) part[j] = lsum[j] * fexp2(lmx[j] - gmx[j]);
#pragma unroll
    for (int off = 1; off < 16; off <<= 1)
#pragma unroll
        for (int j = 0; j < 4; ++j) part[j] += __shfl_xor(part[j], off);
    f32x4 ginv;
#pragma unroll
    for (int j = 0; j < 4; ++j) ginv[j] = 1.f / part[j];

    // ---- pass B: recompute S, emit att (f32), Pl bf16; PV lagged 1 chunk, d-split ----
    float* gattW = att_out + ((size_t)bh * 1024 + q0) * 1024;
    const __bf16* Vb = vt_ws + (size_t)bh * 65536 + (size_t)(w * 16 + lo) * 1024 + hi * 8;
    f32x4 oacc[4] = {};

    STAGE_LOAD(0); STAGE_WRITE(0);
    __syncthreads();
    for (int c = 0; c < 16; ++c) {
        if (c < 15) STAGE_LOAD(c + 1);
        f32x4 s[4];
        SCHUNK(c & 1, s);
#pragma unroll
        for (int kk = 0; kk < 4; ++kk)
#pragma unroll
            for (int j = 0; j < 4; ++j) {
                float p = fexp2(s[kk][j] - gmx[j]) * ginv[j];
                gattW[(size_t)(hi * 4 + j) * 1024 + c * 64 + kk * 16 + lo] = p;
                Pl[c & 1][w][hi * 4 + j][kk * 16 + lo] = (__bf16)p;
            }
        if (c > 0) {
            int pb = (c - 1) & 1;
            const __bf16* vp = Vb + (size_t)(c - 1) * 64;
            bf16x8 vb0 = *(const bf16x8*)vp;
            bf16x8 vb1 = *(const bf16x8*)(vp + 32);
#pragma unroll
            for (int g = 0; g < 4; ++g) {
                bf16x8 pa0 = *(const bf16x8*)&Pl[pb][g][lo][hi * 8];
                bf16x8 pa1 = *(const bf16x8*)&Pl[pb][g][lo][hi * 8 + 32];
                oacc[g] = MFMA16(pa0, vb0, oacc[g]);
                oacc[g] = MFMA16(pa1, vb1, oacc[g]);
            }
        }
        if (c < 15) STAGE_WRITE((c + 1) & 1);
        __syncthreads();
    }
    {
        const __bf16* vp = Vb + (size_t)15 * 64;
        bf16x8 vb0 = *(const bf16x8*)vp;
        bf16x8 vb1 = *(const bf16x8*)(vp + 32);
#pragma unroll
        for (int g = 0; g < 4; ++g) {
            bf16x8 pa0 = *(const bf16x8*)&Pl[1][g][lo][hi * 8];
            bf16x8 pa1 = *(const bf16x8*)&Pl[1][g][lo][hi * 8 + 32];
            oacc[g] = MFMA16(pa0, vb0, oacc[g]);
            oacc[g] = MFMA16(pa1, vb1, oacc[g]);
        }
    }

    int b = bh >> 3, h = bh & 7;
#pragma unroll
    for (int g = 0; g < 4; ++g)
#pragma unroll
        for (int j = 0; j < 4; ++j)
            values[((size_t)b * 1024 + qt * 64 + g * 16 + hi * 4 + j) * 512
                   + h * 64 + w * 16 + lo] = (__bf16)oacc[g][j];
#undef STAGE_LOAD
#undef STAGE_WRITE
#undef SCHUNK
}

// ---------------- output GEMM v2: 128x64 tile, 512 blocks (2/CU) ----------------
__global__ __launch_bounds__(256) void k_out_gemm(
    const __bf16* __restrict__ A, const __bf16* __restrict__ W,
    const float* __restrict__ bias, float* __restrict__ out)
{
    const int K = 512;
    __shared__ __align__(16) __bf16 As[128][32];   // 8 KB
    __shared__ __align__(16) __bf16 Bs[64][32];    // 4 KB
    int m0 = blockIdx.x * 128, n0 = blockIdx.y * 64;
    int t = threadIdx.x, w = t >> 6, l = t & 63;
    int lo = l & 15, hi = l >> 4;

    const __bf16* gA0 = A + (size_t)(m0 + (t >> 2)) * K + (t & 3) * 8;
    const __bf16* gA1 = A + (size_t)(m0 + 64 + (t >> 2)) * K + (t & 3) * 8;
    const __bf16* gB  = W + (size_t)(n0 + (t >> 2)) * K + (t & 3) * 8;
    char* lA0 = (char*)&As[0][0] + t * 16;
    char* lA1 = (char*)&As[64][0] + t * 16;
    char* lB  = (char*)&Bs[0][0] + t * 16;

    f32x4 acc[2][4] = {};
    for (int k0 = 0; k0 < K; k0 += 32) {
        gload_lds16(gA0 + k0, lA0);
        gload_lds16(gA1 + k0, lA1);
        gload_lds16(gB + k0, lB);
        __syncthreads();
        bf16x8 af[2], bq[4];
#pragma unroll
        for (int mi = 0; mi < 2; ++mi) af[mi] = *(const bf16x8*)&As[w * 32 + mi * 16 + lo][hi * 8];
#pragma unroll
        for (int ni = 0; ni < 4; ++ni) bq[ni] = *(const bf16x8*)&Bs[ni * 16 + lo][hi * 8];
#pragma unroll
        for (int mi = 0; mi < 2; ++mi)
#pragma unroll
            for (int ni = 0; ni < 4; ++ni)
                acc[mi][ni] = MFMA16(af[mi], bq[ni], acc[mi][ni]);
        __syncthreads();
    }

#pragma unroll
    for (int ni = 0; ni < 4; ++ni) {
        int n = n0 + ni * 16 + lo;
        float bn = bias[n];
#pragma unroll
        for (int mi = 0; mi < 2; ++mi)
#pragma unroll
            for (int j = 0; j < 4; ++j) {
                int m = m0 + w * 32 + mi * 16 + hi * 4 + j;
                out[(size_t)m * 512 + n] = acc[mi][ni][j] + bn;
            }
    }
}

extern "C" void kernel_launch(void* const* d_in, const int* in_sizes, int n_in,
                              void* d_out, int out_size, void* d_ws, size_t ws_size,
                              hipStream_t stream)
{
    const float* x    = (const float*)d_in[0];
    const float* inp  = (const float*)d_in[1];
    const float* Wqkv = (const float*)d_in[2];
    const float* bqkv = (const float*)d_in[3];
    const float* Wo   = (const float*)d_in[4];
    const float* bo   = (const float*)d_in[5];

    float* out_o   = (float*)d_out;
    float* out_att = out_o + (size_t)8 * 1024 * 512;

    char* ws = (char*)d_ws;
    __bf16* xc    = (__bf16*)(ws + 0);
    __bf16* wq    = (__bf16*)(ws + 9437184);
    __bf16* wo    = (__bf16*)(ws + 11206656);
    __bf16* q_ws  = (__bf16*)(ws + 11730944);
    __bf16* k_ws  = (__bf16*)(ws + 20119552);
    __bf16* vt_ws = (__bf16*)(ws + 28508160);
    __bf16* vals  = (__bf16*)(ws + 36896768);

    k_convert<<<2864, 256, 0, stream>>>(x, inp, Wqkv, Wo, xc, wq, wo);
    k_qkv_gemm<<<dim3(64, 12), 256, 0, stream>>>(xc, wq, bqkv, q_ws, k_ws, vt_ws);
    k_attn<<<1024, 256, 0, stream>>>(q_ws, k_ws, vt_ws, out_att, vals);
    k_out_gemm<<<dim3(64, 8), 256, 0, stream>>>(vals, wo, bo, out_o);
}

// Round 22
// 123.292 us; speedup vs baseline: 1.0575x; 1.0003x over previous
//
#include <hip/hip_runtime.h>

typedef __bf16 bf16x8 __attribute__((ext_vector_type(8)));
typedef __bf16 bf16x4 __attribute__((ext_vector_type(4)));
typedef float f32x4 __attribute__((ext_vector_type(4)));

#define MFMA16(a,b,c) __builtin_amdgcn_mfma_f32_16x16x32_bf16((a),(b),(c),0,0,0)

__device__ __forceinline__ float fexp2(float x) { return __builtin_amdgcn_exp2f(x); }

__device__ __forceinline__ void gload_lds16(const void* g, void* l) {
    __builtin_amdgcn_global_load_lds(
        (const __attribute__((address_space(1))) void*)g,
        (__attribute__((address_space(3))) void*)l, 16, 0, 0);
}

// Problem constants: B=8 S=1024 IN=512 ORIG=64 E=512 H=8 hd=64
// q pre-scaled by 0.125*log2(e): softmax in base-2

__global__ __launch_bounds__(256) void k_convert(
    const float* __restrict__ x, const float* __restrict__ inp,
    const float* __restrict__ Wqkv, const float* __restrict__ Wo,
    __bf16* __restrict__ xc, __bf16* __restrict__ wq, __bf16* __restrict__ wo)
{
    const unsigned C1 = 589824u;
    const unsigned C2 = 110592u;
    unsigned i = blockIdx.x * 256u + threadIdx.x;
    if (i < C1) {
        unsigned e = i * 8u;
        unsigned m = e / 576u, k = e - m * 576u;
        const float* p = (k < 512u) ? x + (size_t)m * 512u + k
                                    : inp + (size_t)m * 64u + (k - 512u);
        f32x4 a = *(const f32x4*)p, b = *(const f32x4*)(p + 4);
        bf16x8 o;
#pragma unroll
        for (int j = 0; j < 4; ++j) { o[j] = (__bf16)a[j]; o[j + 4] = (__bf16)b[j]; }
        *(bf16x8*)&xc[e] = o;
    } else if (i < C1 + C2) {
        unsigned e = (i - C1) * 8u;
        f32x4 a = *(const f32x4*)&Wqkv[e], b = *(const f32x4*)&Wqkv[e + 4];
        bf16x8 o;
#pragma unroll
        for (int j = 0; j < 4; ++j) { o[j] = (__bf16)a[j]; o[j + 4] = (__bf16)b[j]; }
        *(bf16x8*)&wq[e] = o;
    } else {
        unsigned e = (i - C1 - C2) * 8u;
        f32x4 a = *(const f32x4*)&Wo[e], b = *(const f32x4*)&Wo[e + 4];
        bf16x8 o;
#pragma unroll
        for (int j = 0; j < 4; ++j) { o[j] = (__bf16)a[j]; o[j + 4] = (__bf16)b[j]; }
        *(bf16x8*)&wo[e] = o;
    }
}

// ---------------- QKV GEMM v5: BK=32, 3-buffer rotation, counted-vmcnt barrier (T4) ----------------
__global__ __launch_bounds__(256) void k_qkv_gemm(
    const __bf16* __restrict__ A, const __bf16* __restrict__ W,
    const float* __restrict__ bias,
    __bf16* __restrict__ q_ws, __bf16* __restrict__ k_ws, __bf16* __restrict__ vt_ws)
{
    const int K = 576;
    __shared__ __align__(16) char smem[49152];   // 3 x 16KB: As 8K + Bs 8K per buffer
    int m0 = blockIdx.x * 128, n0 = blockIdx.y * 128;
    int t = threadIdx.x, w = t >> 6, l = t & 63;
    int lo = l & 15, hi = l >> 4;
    int wr = w >> 1, wc = w & 1;

    const __bf16* gA = A + (size_t)(m0 + w * 16 + (l >> 2)) * K + (l & 3) * 8;
    const __bf16* gB = W + (size_t)(n0 + w * 16 + (l >> 2)) * K + (l & 3) * 8;

    float bias_reg[4];
#pragma unroll
    for (int ni = 0; ni < 4; ++ni) bias_reg[ni] = bias[n0 + wc * 64 + ni * 16 + lo];

#define QSTAGE(k0, buf) { char* b_ = smem + (buf) * 16384; \
                          gload_lds16(gA + (k0), b_ + w * 1024); \
                          gload_lds16(gA + 64 * K + (k0), b_ + 4096 + w * 1024); \
                          gload_lds16(gB + (k0), b_ + 8192 + w * 1024); \
                          gload_lds16(gB + 64 * K + (k0), b_ + 12288 + w * 1024); }

    f32x4 acc[4][4] = {};
    QSTAGE(0, 0);
    QSTAGE(32, 1);
    for (int it = 0; it < 18; ++it) {
        __builtin_amdgcn_sched_barrier(0);
        if (it < 17) asm volatile("s_waitcnt vmcnt(4) lgkmcnt(0)" ::: "memory");
        else         asm volatile("s_waitcnt vmcnt(0) lgkmcnt(0)" ::: "memory");
        __builtin_amdgcn_s_barrier();
        __builtin_amdgcn_sched_barrier(0);
        if (it < 16) QSTAGE((it + 2) * 32, (it + 2) % 3);
        const __bf16 (*As)[32] = (const __bf16 (*)[32])(smem + (it % 3) * 16384);
        const __bf16 (*Bs)[32] = (const __bf16 (*)[32])(smem + (it % 3) * 16384 + 8192);
        bf16x8 af[4], bq[4];
#pragma unroll
        for (int mi = 0; mi < 4; ++mi) af[mi] = *(const bf16x8*)&As[wr * 64 + mi * 16 + lo][hi * 8];
#pragma unroll
        for (int ni = 0; ni < 4; ++ni) bq[ni] = *(const bf16x8*)&Bs[wc * 64 + ni * 16 + lo][hi * 8];
#pragma unroll
        for (int mi = 0; mi < 4; ++mi)
#pragma unroll
            for (int ni = 0; ni < 4; ++ni)
                acc[mi][ni] = MFMA16(af[mi], bq[ni], acc[mi][ni]);
    }
#undef QSTAGE
    // epilogue Ep regions [0,17408) are disjoint from buf2 [32768,49152): no barrier needed
    __builtin_amdgcn_sched_barrier(0);

    int q64 = (n0 >> 6) + wc;
    int head = q64 / 3, part = q64 - head * 3;
    int mbase = m0 + wr * 64;
    size_t bh = (size_t)((mbase >> 10) * 8 + head);
    int sbase = mbase & 1023;

    if (part < 2) {
        float scale = (part == 0) ? 0.180336881f : 1.0f;   // 0.125*log2e on q
        __bf16* dst = (part == 0 ? q_ws : k_ws) + (bh * 1024 + sbase) * 64;
        __bf16 (*Ep)[68] = (__bf16 (*)[68])(smem + w * 4352);
#pragma unroll
        for (int hh = 0; hh < 2; ++hh) {
#pragma unroll
            for (int mi2 = 0; mi2 < 2; ++mi2) {
                int mi = hh * 2 + mi2;
#pragma unroll
                for (int ni = 0; ni < 4; ++ni)
#pragma unroll
                    for (int j = 0; j < 4; ++j)
                        Ep[mi2 * 16 + hi * 4 + j][ni * 16 + lo] =
                            (__bf16)((acc[mi][ni][j] + bias_reg[ni]) * scale);
            }
#pragma unroll
            for (int it = 0; it < 4; ++it) {
                int r = it * 8 + (l >> 3);
                bf16x8 v = *(const bf16x8*)&Ep[r][(l & 7) * 8];
                *(bf16x8*)&dst[(size_t)(hh * 32 + r) * 64 + (l & 7) * 8] = v;
            }
        }
    } else {
        __bf16* dst = vt_ws + bh * 65536 + sbase;
        __bf16 (*Ep)[34] = (__bf16 (*)[34])(smem + w * 4352);
#pragma unroll
        for (int hh = 0; hh < 2; ++hh) {
#pragma unroll
            for (int mi2 = 0; mi2 < 2; ++mi2) {
                int mi = hh * 2 + mi2;
#pragma unroll
                for (int ni = 0; ni < 4; ++ni)
#pragma unroll
                    for (int j = 0; j < 4; ++j)
                        Ep[ni * 16 + lo][mi2 * 16 + hi * 4 + j] =
                            (__bf16)(acc[mi][ni][j] + bias_reg[ni]);
            }
#pragma unroll
            for (int it = 0; it < 4; ++it) {
                int d = it * 16 + (l >> 2);
                bf16x8 v = *(const bf16x8*)&Ep[d][(l & 3) * 8];
                *(bf16x8*)&dst[(size_t)d * 1024 + hh * 32 + (l & 3) * 8] = v;
            }
        }
    }
}

// ---------------- fused attention v15: v10 structure, exp2 softmax ----------------
__global__ __launch_bounds__(256, 4) void k_attn(
    const __bf16* __restrict__ q_ws, const __bf16* __restrict__ k_ws,
    const __bf16* __restrict__ vt_ws,
    float* __restrict__ att_out, __bf16* __restrict__ values)
{
    __shared__ __align__(16) __bf16 Klds[2][64][76];
    __shared__ __align__(16) __bf16 Pl[2][4][16][76];

    int bid = blockIdx.x;
    int nid = (bid & 7) * 128 + (bid >> 3);
    int bh = nid >> 4, qt = nid & 15;
    int t = threadIdx.x, w = t >> 6, l = t & 63;
    int lo = l & 15, hi = l >> 4;
    int q0 = qt * 64 + w * 16;

    const __bf16* Qg = q_ws + ((size_t)bh * 1024 + q0 + lo) * 64 + hi * 8;
    bf16x8 qa0 = *(const bf16x8*)Qg;
    bf16x8 qa1 = *(const bf16x8*)(Qg + 32);

    const __bf16* Kb = k_ws + (size_t)bh * 65536;
    int srow = t >> 2, scol = (t & 3) * 16;
    const __bf16* gK = Kb + (size_t)srow * 64 + scol;
    bf16x8 r0, r1;

#define STAGE_LOAD(c)  { const __bf16* p_ = gK + (size_t)(c) * 4096; \
                         r0 = *(const bf16x8*)p_; r1 = *(const bf16x8*)(p_ + 8); }
#define STAGE_WRITE(b) { *(bf16x8*)&Klds[b][srow][scol] = r0; \
                         *(bf16x8*)&Klds[b][srow][scol + 8] = r1; }
#define SCHUNK(b, s)   _Pragma("unroll") \
                       for (int kk = 0; kk < 4; ++kk) { \
                           bf16x8 kb0 = *(const bf16x8*)&Klds[b][kk * 16 + lo][hi * 8]; \
                           bf16x8 kb1 = *(const bf16x8*)&Klds[b][kk * 16 + lo][hi * 8 + 32]; \
                           f32x4 a_ = {}; \
                           a_ = MFMA16(qa0, kb0, a_); \
                           a_ = MFMA16(qa1, kb1, a_); \
                           s[kk] = a_; \
                       }

    // ---- pass A: online (max, sum) per lane; base-2 ----
    f32x4 lmx = { -3.4e38f, -3.4e38f, -3.4e38f, -3.4e38f };
    f32x4 lsum = {};
    STAGE_LOAD(0); STAGE_WRITE(0);
    __syncthreads();
    for (int c = 0; c < 16; ++c) {
        if (c < 15) STAGE_LOAD(c + 1);
        f32x4 s[4];
        SCHUNK(c & 1, s);
#pragma unroll
        for (int j = 0; j < 4; ++j) {
            float cm = fmaxf(fmaxf(s[0][j], s[1][j]), fmaxf(s[2][j], s[3][j]));
            float nm = fmaxf(lmx[j], cm);
            float a = fexp2(s[0][j] - nm) + fexp2(s[1][j] - nm)
                    + fexp2(s[2][j] - nm) + fexp2(s[3][j] - nm);
            lsum[j] = lsum[j] * fexp2(lmx[j] - nm) + a;
            lmx[j] = nm;
        }
        if (c < 15) STAGE_WRITE((c + 1) & 1);
        __syncthreads();
    }
    f32x4 gmx = lmx;
#pragma unroll
    for (int off = 1; off < 16; off <<= 1)
#pragma unroll
        for (int j = 0; j < 4; ++j) gmx[j] = fmaxf(gmx[j], __shfl_xor(gmx[j], off));
    f32x4 part;
#pragma unroll
    for (int j = 0; j < 4; ++j) part[j] = lsum[j] * fexp2(lmx[j] - gmx[j]);
#pragma unroll
    for (int off = 1; off < 16; off <<= 1)
#pragma unroll
        for (int j = 0; j < 4; ++j) part[j] += __shfl_xor(part[j], off);
    f32x4 ginv;
#pragma unroll
    for (int j = 0; j < 4; ++j) ginv[j] = 1.f / part[j];

    // ---- pass B: recompute S, emit att (f32), Pl bf16; PV lagged 1 chunk, d-split ----
    float* gattW = att_out + ((size_t)bh * 1024 + q0) * 1024;
    const __bf16* Vb = vt_ws + (size_t)bh * 65536 + (size_t)(w * 16 + lo) * 1024 + hi * 8;
    f32x4 oacc[4] = {};

    STAGE_LOAD(0); STAGE_WRITE(0);
    __syncthreads();
    for (int c = 0; c < 16; ++c) {
        if (c < 15) STAGE_LOAD(c + 1);
        f32x4 s[4];
        SCHUNK(c & 1, s);
#pragma unroll
        for (int kk = 0; kk < 4; ++kk)
#pragma unroll
            for (int j = 0; j < 4; ++j) {
                float p = fexp2(s[kk][j] - gmx[j]) * ginv[j];
                gattW[(size_t)(hi * 4 + j) * 1024 + c * 64 + kk * 16 + lo] = p;
                Pl[c & 1][w][hi * 4 + j][kk * 16 + lo] = (__bf16)p;
            }
        if (c > 0) {
            int pb = (c - 1) & 1;
            const __bf16* vp = Vb + (size_t)(c - 1) * 64;
            bf16x8 vb0 = *(const bf16x8*)vp;
            bf16x8 vb1 = *(const bf16x8*)(vp + 32);
#pragma unroll
            for (int g = 0; g < 4; ++g) {
                bf16x8 pa0 = *(const bf16x8*)&Pl[pb][g][lo][hi * 8];
                bf16x8 pa1 = *(const bf16x8*)&Pl[pb][g][lo][hi * 8 + 32];
                oacc[g] = MFMA16(pa0, vb0, oacc[g]);
                oacc[g] = MFMA16(pa1, vb1, oacc[g]);
            }
        }
        if (c < 15) STAGE_WRITE((c + 1) & 1);
        __syncthreads();
    }
    {
        const __bf16* vp = Vb + (size_t)15 * 64;
        bf16x8 vb0 = *(const bf16x8*)vp;
        bf16x8 vb1 = *(const bf16x8*)(vp + 32);
#pragma unroll
        for (int g = 0; g < 4; ++g) {
            bf16x8 pa0 = *(const bf16x8*)&Pl[1][g][lo][hi * 8];
            bf16x8 pa1 = *(const bf16x8*)&Pl[1][g][lo][hi * 8 + 32];
            oacc[g] = MFMA16(pa0, vb0, oacc[g]);
            oacc[g] = MFMA16(pa1, vb1, oacc[g]);
        }
    }

    int b = bh >> 3, h = bh & 7;
#pragma unroll
    for (int g = 0; g < 4; ++g)
#pragma unroll
        for (int j = 0; j < 4; ++j)
            values[((size_t)b * 1024 + qt * 64 + g * 16 + hi * 4 + j) * 512
                   + h * 64 + w * 16 + lo] = (__bf16)oacc[g][j];
#undef STAGE_LOAD
#undef STAGE_WRITE
#undef SCHUNK
}

// ---------------- output GEMM v2: 128x64 tile, 512 blocks (2/CU) ----------------
__global__ __launch_bounds__(256) void k_out_gemm(
    const __bf16* __restrict__ A, const __bf16* __restrict__ W,
    const float* __restrict__ bias, float* __restrict__ out)
{
    const int K = 512;
    __shared__ __align__(16) __bf16 As[128][32];   // 8 KB
    __shared__ __align__(16) __bf16 Bs[64][32];    // 4 KB
    int m0 = blockIdx.x * 128, n0 = blockIdx.y * 64;
    int t = threadIdx.x, w = t >> 6, l = t & 63;
    int lo = l & 15, hi = l >> 4;

    const __bf16* gA0 = A + (size_t)(m0 + (t >> 2)) * K + (t & 3) * 8;
    const __bf16* gA1 = A + (size_t)(m0 + 64 + (t >> 2)) * K + (t & 3) * 8;
    const __bf16* gB  = W + (size_t)(n0 + (t >> 2)) * K + (t & 3) * 8;
    char* lA0 = (char*)&As[0][0] + t * 16;
    char* lA1 = (char*)&As[64][0] + t * 16;
    char* lB  = (char*)&Bs[0][0] + t * 16;

    f32x4 acc[2][4] = {};
    for (int k0 = 0; k0 < K; k0 += 32) {
        gload_lds16(gA0 + k0, lA0);
        gload_lds16(gA1 + k0, lA1);
        gload_lds16(gB + k0, lB);
        __syncthreads();
        bf16x8 af[2], bq[4];
#pragma unroll
        for (int mi = 0; mi < 2; ++mi) af[mi] = *(const bf16x8*)&As[w * 32 + mi * 16 + lo][hi * 8];
#pragma unroll
        for (int ni = 0; ni < 4; ++ni) bq[ni] = *(const bf16x8*)&Bs[ni * 16 + lo][hi * 8];
#pragma unroll
        for (int mi = 0; mi < 2; ++mi)
#pragma unroll
            for (int ni = 0; ni < 4; ++ni)
                acc[mi][ni] = MFMA16(af[mi], bq[ni], acc[mi][ni]);
        __syncthreads();
    }

#pragma unroll
    for (int ni = 0; ni < 4; ++ni) {
        int n = n0 + ni * 16 + lo;
        float bn = bias[n];
#pragma unroll
        for (int mi = 0; mi < 2; ++mi)
#pragma unroll
            for (int j = 0; j < 4; ++j) {
                int m = m0 + w * 32 + mi * 16 + hi * 4 + j;
                out[(size_t)m * 512 + n] = acc[mi][ni][j] + bn;
            }
    }
}

extern "C" void kernel_launch(void* const* d_in, const int* in_sizes, int n_in,
                              void* d_out, int out_size, void* d_ws, size_t ws_size,
                              hipStream_t stream)
{
    const float* x    = (const float*)d_in[0];
    const float* inp  = (const float*)d_in[1];
    const float* Wqkv = (const float*)d_in[2];
    const float* bqkv = (const float*)d_in[3];
    const float* Wo   = (const float*)d_in[4];
    const float* bo   = (const float*)d_in[5];

    float* out_o   = (float*)d_out;
    float* out_att = out_o + (size_t)8 * 1024 * 512;

    char* ws = (char*)d_ws;
    __bf16* xc    = (__bf16*)(ws + 0);
    __bf16* wq    = (__bf16*)(ws + 9437184);
    __bf16* wo    = (__bf16*)(ws + 11206656);
    __bf16* q_ws  = (__bf16*)(ws + 11730944);
    __bf16* k_ws  = (__bf16*)(ws + 20119552);
    __bf16* vt_ws = (__bf16*)(ws + 28508160);
    __bf16* vals  = (__bf16*)(ws + 36896768);

    k_convert<<<2864, 256, 0, stream>>>(x, inp, Wqkv, Wo, xc, wq, wo);
    k_qkv_gemm<<<dim3(64, 12), 256, 0, stream>>>(xc, wq, bqkv, q_ws, k_ws, vt_ws);
    k_attn<<<1024, 256, 0, stream>>>(q_ws, k_ws, vt_ws, out_att, vals);
    k_out_gemm<<<dim3(64, 8), 256, 0, stream>>>(vals, wo, bo, out_o);
}